// Round 9
// baseline (436.272 us; speedup 1.0000x reference)
//
#include <hip/hip_runtime.h>

// N=384 spatial, C=128 channels (CZ=CH=128). Two tri-mul passes (outgoing, incoming).
// ws layout: [12 swizzled bf16 weight mats | a_t | b_t | p_t], each big buf NN*128 bf16.

constexpr int NS = 384;
constexpr int NN = NS * NS;

using bf16x8 = __attribute__((ext_vector_type(8))) __bf16;
using bf16x4 = __attribute__((ext_vector_type(4))) __bf16;
using f32x4  = __attribute__((ext_vector_type(4))) float;

// 1/(1+e^-x) with an explicit v_rcp_f32 (ISA: D=1/S0, ~1ulp) instead of the precise
// division chain (~10 instr). Error invisible at bf16 output precision. (verified r3)
__device__ inline float fast_sigmoid(float x) {
  float d = 1.0f + __expf(-x);
  float r;
  asm("v_rcp_f32 %0, %1" : "=v"(r) : "v"(d));
  return r;
}

// ---------------- K0: weight fp32 -> bf16, swizzled to MFMA fragment order ------------
// Fragment slot layout per matrix: idx = ((s*8 + t)*64 + lane)*8 + j  holds
// W[32*s + 8*(lane>>4) + j][16*t + (lane&15)].  (Works as A-op (W^T) or B-op (W).)
__global__ __launch_bounds__(256) void prep_weights(
    const float* __restrict__ w_ag, const float* __restrict__ w_ap,
    const float* __restrict__ w_bg, const float* __restrict__ w_bp,
    const float* __restrict__ w_g,  const float* __restrict__ w_z,
    __bf16* __restrict__ wsw)
{
  int gid  = blockIdx.x * 256 + threadIdx.x;   // 96*256 = 24576 = 12*2048
  int mat  = gid >> 11;
  int slot = gid & 2047;
  int lane = slot & 63;
  int tb   = (slot >> 6) & 7;
  int s    = slot >> 9;
  int pass = mat / 6, which = mat % 6;
  const float* W;
  switch (which) {
    case 0: W = w_ag; break; case 1: W = w_ap; break; case 2: W = w_bg; break;
    case 3: W = w_bp; break; case 4: W = w_g;  break; default: W = w_z;
  }
  W += pass * 16384;
  int n0 = tb * 16 + (lane & 15);
  int k0 = s * 32 + (lane >> 4) * 8;
  __bf16* dst = wsw + ((size_t)mat * 2048 + slot) * 8;
#pragma unroll
  for (int j = 0; j < 8; ++j) dst[j] = (__bf16)W[(k0 + j) * 128 + n0];
}

// Shared LN loader: interleaved channel assignment so load-instruction u fetches bytes
// [u*64, u*64+64) of each of the wave's 16 rows (16 fully-used cache lines / instr,
// vs 64 quarter-used lines in row-sequential order). Thread (row,q) owns channels
// {16u + 4q + j}. sched_barrier(0) pins all 8 loads before the math => 8-deep MLP.
// (verified r7: proj 71->63, out -15us)
template <typename DstRow>
__device__ inline void ln_row_interleaved(const float* __restrict__ zrow, int q,
                                          const float* __restrict__ lnw,
                                          const float* __restrict__ lnb,
                                          DstRow dstrow)
{
  const float4* zp = (const float4*)zrow;
  float4 v[8];
#pragma unroll
  for (int u = 0; u < 8; ++u) v[u] = zp[u * 4 + q];
  __builtin_amdgcn_sched_barrier(0);
  float s1 = 0.f, s2 = 0.f;
#pragma unroll
  for (int u = 0; u < 8; ++u) {
    float4 t = v[u];
    s1 += t.x + t.y + t.z + t.w;
    s2 += t.x * t.x + t.y * t.y + t.z * t.z + t.w * t.w;
  }
  s1 += __shfl_xor(s1, 1); s2 += __shfl_xor(s2, 1);
  s1 += __shfl_xor(s1, 2); s2 += __shfl_xor(s2, 2);
  float mean = s1 * (1.0f / 128.0f);
  float var  = s2 * (1.0f / 128.0f) - mean * mean;
  float rstd = rsqrtf(var + 1e-5f);
#pragma unroll
  for (int u = 0; u < 8; ++u) {
    int c0 = u * 16 + q * 4;
    float4 t  = v[u];
    float4 w4 = *(const float4*)(lnw + c0);
    float4 b4 = *(const float4*)(lnb + c0);
    dstrow[c0 + 0] = (__bf16)((t.x - mean) * rstd * w4.x + b4.x);
    dstrow[c0 + 1] = (__bf16)((t.y - mean) * rstd * w4.y + b4.y);
    dstrow[c0 + 2] = (__bf16)((t.z - mean) * rstd * w4.z + b4.z);
    dstrow[c0 + 3] = (__bf16)((t.w - mean) * rstd * w4.w + b4.w);
  }
}

// ---------------- K2: LN(z) + a, b projections (gates fused) --------------------------
// 128 positions per block (r8, neutral-verified): amortizes per-block weight loads.
// mode 0 (outgoing): block = 128 consecutive positions (row-block).
// mode 1 (incoming): block = 128 positions down a column -> transposed a_t/b_t writes
//                    stay coalesced.
// Output orientation: mfma(znf, fW) -> D[pos][c]; lane's 4 regs are 4 consecutive
// positions of one channel => single 8B store into the [c][pos] layout.
// z fragments re-read from LDS per (set,nt) (keeps VGPR low -> high occupancy, r4).
__global__ __launch_bounds__(256) void proj_kernel(
    const float* __restrict__ zsrc, const float* __restrict__ lnw, const float* __restrict__ lnb,
    const __bf16* __restrict__ wsw5,
    const float* __restrict__ bag, const float* __restrict__ bap,
    const float* __restrict__ bbg, const float* __restrict__ bbp,
    __bf16* __restrict__ a_t, __bf16* __restrict__ b_t, int mode)
{
  __shared__ __bf16 zn[128][136];   // padded pitch: conflict-free b128
  int tid = threadIdx.x;
  int rb = 0, r2 = 0;
  size_t pstart = 0;
  if (mode == 0) pstart = (size_t)blockIdx.x * 128;
  else { rb = blockIdx.x / NS; r2 = blockIdx.x % NS; }   // rb 0..2, r2 0..383

  const int wv = tid >> 6;
  const int lane = tid & 63;
  const int lm = lane & 15;
  const int lq = lane >> 4;

  // ---- phase 1: LayerNorm 128 rows x 128 ch, 4 threads/row, two sequential halves ----
  {
    int row = tid >> 2, q = tid & 3;
#pragma unroll
    for (int half = 0; half < 2; ++half) {
      int r = row + 64 * half;
      size_t zoff = (mode == 0) ? (pstart + r) * 128
                                : ((size_t)(128 * rb + r) * NS + r2) * 128;
      ln_row_interleaved(zsrc + zoff, q, lnw, lnb, &zn[r][0]);
    }
  }
  __syncthreads();

  // ---- phase 2: MFMA projections ----
  const size_t wposbase = (mode == 0) ? pstart : ((size_t)r2 * NS + 128 * rb);

  // sets: 0=(a,mb0) 1=(a,mb1) 2=(b,mb0) 3=(b,mb1)
#pragma unroll
  for (int set = 0; set < 4; ++set) {
    const int grp = set >> 1, mbi = set & 1;
    const int mb = 2 * wv + mbi;   // c_out 16-tile handled by this wave
    const __bf16* wG = wsw5 + (size_t)(2 * grp) * 16384;   // gate weights
    const __bf16* wP = wG + 16384;                         // proj weights
    bf16x8 fG[4], fP[4];
#pragma unroll
    for (int s = 0; s < 4; ++s) {
      fG[s] = *(const bf16x8*)(wG + ((size_t)((s * 8 + mb) * 64 + lane)) * 8);
      fP[s] = *(const bf16x8*)(wP + ((size_t)((s * 8 + mb) * 64 + lane)) * 8);
    }
    const int cc = 16 * mb + lm;       // this lane's output channel
    const float bG = (grp ? bbg : bag)[cc];
    const float bP = (grp ? bbp : bap)[cc];
    __bf16* dst = grp ? b_t : a_t;
    __bf16* drow = dst + (size_t)cc * NN + wposbase + 4 * lq;
#pragma unroll
    for (int nt = 0; nt < 8; ++nt) {
      // z fragments re-read from LDS each iteration (trades LDS BW for registers)
      bf16x8 z0 = *(const bf16x8*)(&zn[16 * nt + lm][8 * lq]);
      bf16x8 z1 = *(const bf16x8*)(&zn[16 * nt + lm][32 + 8 * lq]);
      bf16x8 z2 = *(const bf16x8*)(&zn[16 * nt + lm][64 + 8 * lq]);
      bf16x8 z3 = *(const bf16x8*)(&zn[16 * nt + lm][96 + 8 * lq]);
      f32x4 acc0 = {0.f, 0.f, 0.f, 0.f}, acc1 = {0.f, 0.f, 0.f, 0.f};
      acc0 = __builtin_amdgcn_mfma_f32_16x16x32_bf16(z0, fG[0], acc0, 0, 0, 0);
      acc1 = __builtin_amdgcn_mfma_f32_16x16x32_bf16(z0, fP[0], acc1, 0, 0, 0);
      acc0 = __builtin_amdgcn_mfma_f32_16x16x32_bf16(z1, fG[1], acc0, 0, 0, 0);
      acc1 = __builtin_amdgcn_mfma_f32_16x16x32_bf16(z1, fP[1], acc1, 0, 0, 0);
      acc0 = __builtin_amdgcn_mfma_f32_16x16x32_bf16(z2, fG[2], acc0, 0, 0, 0);
      acc1 = __builtin_amdgcn_mfma_f32_16x16x32_bf16(z2, fP[2], acc1, 0, 0, 0);
      acc0 = __builtin_amdgcn_mfma_f32_16x16x32_bf16(z3, fG[3], acc0, 0, 0, 0);
      acc1 = __builtin_amdgcn_mfma_f32_16x16x32_bf16(z3, fP[3], acc1, 0, 0, 0);
      // D[pos][c]: pos = 16*nt + 4*lq + r (local), c = 16*mb + lm
      bf16x4 pk;
#pragma unroll
      for (int r = 0; r < 4; ++r) {
        float xg = acc0[r] + bG;
        float xp = acc1[r] + bP;
        pk[r] = (__bf16)(xp * fast_sigmoid(xg));
      }
      *(bf16x4*)(drow + 16 * nt) = pk;
    }
  }
}

// ---------------- K3: triangle einsum, per-channel 384x384x384 NT GEMM ----------------
// P[c][i][k] = sum_j A[c][i][j] * B[c][k][j].  128x128 tile/block, barrier-FREE (r9):
// MFMA fragments are read directly from global/L2 — per instruction lanes (lm,lq) touch
// 16 rows x one fully-used 64B line (the r7-verified line-efficient pattern). The
// panels are L2-resident per XCD (channel-chunk swizzle), so the old LDS staging's
// 2-barriers-per-K-step (vmcnt(0) drain x3 iters, never pipelined at K=384) was pure
// overhead. No LDS, no syncthreads, waves free-run and hide ~200cy L2 latency.
// k index: 32*s + 8*lq, s=0..11 (algebraically identical to the old staged+XOR path).
__global__ __launch_bounds__(256) void tri_kernel(
    const __bf16* __restrict__ a_t, const __bf16* __restrict__ b_t, __bf16* __restrict__ p_t)
{
  int lin = blockIdx.x;            // 0..1151
  int xcd = lin & 7;
  int loc = lin >> 3;              // 0..143
  int cq  = loc / 9;               // 0..15
  int tile = loc - 9 * cq;         // 0..8
  int c  = (xcd << 4) | cq;
  int i0 = (tile % 3) * 128, k0 = (tile / 3) * 128;
  int tid = threadIdx.x, wv = tid >> 6, lane = tid & 63;
  int lm = lane & 15, lq = lane >> 4;
  const int rowA = i0 + 64 * (wv & 1);   // wave's 64-row A strip
  const int rowB = k0 + 64 * (wv >> 1);  // wave's 64-row B strip
  const __bf16* Ab = a_t + (size_t)c * NN + (size_t)(rowA + lm) * NS + 8 * lq;
  const __bf16* Bb = b_t + (size_t)c * NN + (size_t)(rowB + lm) * NS + 8 * lq;
  f32x4 acc[4][4];
#pragma unroll
  for (int mi = 0; mi < 4; ++mi)
#pragma unroll
    for (int ni = 0; ni < 4; ++ni) acc[mi][ni] = {0.f, 0.f, 0.f, 0.f};

#pragma unroll 2
  for (int s = 0; s < 12; ++s) {
    bf16x8 afr[4], bfr[4];
#pragma unroll
    for (int mi = 0; mi < 4; ++mi)
      afr[mi] = *(const bf16x8*)(Ab + (size_t)(16 * mi) * NS + 32 * s);
#pragma unroll
    for (int ni = 0; ni < 4; ++ni)
      bfr[ni] = *(const bf16x8*)(Bb + (size_t)(16 * ni) * NS + 32 * s);
#pragma unroll
    for (int mi = 0; mi < 4; ++mi)
#pragma unroll
      for (int ni = 0; ni < 4; ++ni)
        acc[mi][ni] = __builtin_amdgcn_mfma_f32_16x16x32_bf16(afr[mi], bfr[ni], acc[mi][ni], 0, 0, 0);
  }
#pragma unroll
  for (int mi = 0; mi < 4; ++mi)
#pragma unroll
    for (int ni = 0; ni < 4; ++ni)
#pragma unroll
      for (int r = 0; r < 4; ++r) {
        int row = rowA + 16 * mi + 4 * lq + r;
        int col = rowB + 16 * ni + lm;
        p_t[(size_t)c * NN + (size_t)row * NS + col] = (__bf16)acc[mi][ni][r];
      }
}

// ---------------- K4: LN(p) @ w_z + b_z, g = sigmoid(LN(z) @ w_g + b_g), out = p*g + z -
__global__ __launch_bounds__(256) void out_kernel(
    const __bf16* __restrict__ p_t,
    const float* __restrict__ z_in, float* __restrict__ z_out,
    const float* __restrict__ lniw, const float* __restrict__ lnib,
    const float* __restrict__ lnow, const float* __restrict__ lnob,
    const __bf16* __restrict__ wz, const float* __restrict__ bz,
    const __bf16* __restrict__ wg, const float* __restrict__ bg)
{
  __shared__ __bf16 pl[64][136];
  __shared__ __bf16 znl[64][136];
  int tid = threadIdx.x;
  size_t base = (size_t)blockIdx.x * 64;

  // A. LayerNorm(z) -> znl
  {
    int row = tid >> 2, q = tid & 3;
    ln_row_interleaved(z_in + (base + row) * 128, q, lniw, lnib, &znl[row][0]);
  }

  // B. load P (c-major) coalesced, transpose into LDS [pos][c]  (r7 version; the r8
  // line-coalesced variant regressed ~4us/dispatch — reverted)
  {
    int c2 = tid >> 1, hf = tid & 1;
    const __bf16* src = p_t + (size_t)c2 * NN + base + hf * 32;
    bf16x8 v0 = ((const bf16x8*)src)[0];
    bf16x8 v1 = ((const bf16x8*)src)[1];
    bf16x8 v2 = ((const bf16x8*)src)[2];
    bf16x8 v3 = ((const bf16x8*)src)[3];
#pragma unroll
    for (int j = 0; j < 8; ++j) pl[hf * 32 + j][c2] = v0[j];
#pragma unroll
    for (int j = 0; j < 8; ++j) pl[hf * 32 + 8 + j][c2] = v1[j];
#pragma unroll
    for (int j = 0; j < 8; ++j) pl[hf * 32 + 16 + j][c2] = v2[j];
#pragma unroll
    for (int j = 0; j < 8; ++j) pl[hf * 32 + 24 + j][c2] = v3[j];
  }
  __syncthreads();

  // C. LayerNorm over c per position (4 threads/row), rewrite pl in place
  {
    int row = tid >> 2, q = tid & 3;
    bf16x8 pv[4];
#pragma unroll
    for (int s = 0; s < 4; ++s) pv[s] = *(const bf16x8*)(&pl[row][q * 32 + 8 * s]);
    float s1 = 0.f, s2 = 0.f;
#pragma unroll
    for (int s = 0; s < 4; ++s)
#pragma unroll
      for (int j = 0; j < 8; ++j) { float f = (float)pv[s][j]; s1 += f; s2 += f * f; }
    s1 += __shfl_xor(s1, 1); s2 += __shfl_xor(s2, 1);
    s1 += __shfl_xor(s1, 2); s2 += __shfl_xor(s2, 2);
    float mean = s1 * (1.0f / 128.0f);
    float var  = s2 * (1.0f / 128.0f) - mean * mean;
    float rstd = rsqrtf(var + 1e-5f);
#pragma unroll
    for (int s = 0; s < 4; ++s) {
#pragma unroll
      for (int j = 0; j < 8; ++j) {
        int cc = q * 32 + 8 * s + j;
        float f = ((float)pv[s][j] - mean) * rstd * lnow[cc] + lnob[cc];
        pv[s][j] = (__bf16)f;
      }
      *(bf16x8*)(&pl[row][q * 32 + 8 * s]) = pv[s];
    }
  }
  __syncthreads();

  // D. GEMMs: p_ln @ w_z  and  zn @ w_g; epilogue: (+b_z) * sigmoid(. + b_g) + z
  int wv = tid >> 6, lane = tid & 63, lm = lane & 15, lq = lane >> 4;
  bf16x8 wzf[2][4], wgf[2][4];
  float bzv[2], bgv[2];
#pragma unroll
  for (int nbi = 0; nbi < 2; ++nbi) {
    int nb = 2 * wv + nbi;
    bzv[nbi] = bz[16 * nb + lm];
    bgv[nbi] = bg[16 * nb + lm];
#pragma unroll
    for (int s = 0; s < 4; ++s) {
      wzf[nbi][s] = *(const bf16x8*)(wz + ((size_t)((s * 8 + nb) * 64 + lane)) * 8);
      wgf[nbi][s] = *(const bf16x8*)(wg + ((size_t)((s * 8 + nb) * 64 + lane)) * 8);
    }
  }
#pragma unroll
  for (int mt = 0; mt < 4; ++mt) {
    bf16x8 af[4], zf[4];
#pragma unroll
    for (int s = 0; s < 4; ++s) {
      af[s] = *(const bf16x8*)(&pl[16 * mt + lm][32 * s + 8 * lq]);
      zf[s] = *(const bf16x8*)(&znl[16 * mt + lm][32 * s + 8 * lq]);
    }
#pragma unroll
    for (int nbi = 0; nbi < 2; ++nbi) {
      f32x4 accp = {0.f, 0.f, 0.f, 0.f};
      f32x4 accg = {0.f, 0.f, 0.f, 0.f};
#pragma unroll
      for (int s = 0; s < 4; ++s) {
        accp = __builtin_amdgcn_mfma_f32_16x16x32_bf16(af[s], wzf[nbi][s], accp, 0, 0, 0);
        accg = __builtin_amdgcn_mfma_f32_16x16x32_bf16(zf[s], wgf[nbi][s], accg, 0, 0, 0);
      }
      int cz = 16 * (2 * wv + nbi) + lm;
#pragma unroll
      for (int r = 0; r < 4; ++r) {
        int pos = 16 * mt + 4 * lq + r;
        size_t idx = (base + pos) * 128 + cz;
        float gv  = fast_sigmoid(accg[r] + bgv[nbi]);
        float res = (accp[r] + bzv[nbi]) * gv + z_in[idx];
        z_out[idx] = res;
      }
    }
  }
}

extern "C" void kernel_launch(void* const* d_in, const int* in_sizes, int n_in,
                              void* d_out, int out_size, void* d_ws, size_t ws_size,
                              hipStream_t stream) {
  (void)in_sizes; (void)n_in; (void)out_size; (void)ws_size;
  const float* z        = (const float*)d_in[0];
  const float* ln_in_w  = (const float*)d_in[1];
  const float* ln_in_b  = (const float*)d_in[2];
  const float* w_ag     = (const float*)d_in[3];
  const float* b_ag     = (const float*)d_in[4];
  const float* w_ap     = (const float*)d_in[5];
  const float* b_ap     = (const float*)d_in[6];
  const float* w_bg     = (const float*)d_in[7];
  const float* b_bg     = (const float*)d_in[8];
  const float* w_bp     = (const float*)d_in[9];
  const float* b_bp     = (const float*)d_in[10];
  const float* ln_out_w = (const float*)d_in[11];
  const float* ln_out_b = (const float*)d_in[12];
  const float* w_z      = (const float*)d_in[13];
  const float* b_z      = (const float*)d_in[14];
  const float* w_g      = (const float*)d_in[15];
  const float* b_g      = (const float*)d_in[16];
  float* out = (float*)d_out;

  __bf16* wsw = (__bf16*)d_ws;              // 12 * 16384 elements
  __bf16* a_t = wsw + 12 * 16384;
  __bf16* b_t = a_t + (size_t)NN * 128;
  __bf16* p_t = b_t + (size_t)NN * 128;

  prep_weights<<<96, 256, 0, stream>>>(w_ag, w_ap, w_bg, w_bp, w_g, w_z, wsw);

  for (int idx = 0; idx < 2; ++idx) {
    const float* zsrc = (idx == 0) ? z : out;
    const __bf16* wsw5 = wsw + (size_t)idx * 6 * 16384;
    proj_kernel<<<1152, 256, 0, stream>>>(
        zsrc, ln_in_w + idx * 128, ln_in_b + idx * 128, wsw5,
        b_ag + idx * 128, b_ap + idx * 128, b_bg + idx * 128, b_bp + idx * 128,
        a_t, b_t, idx);
    tri_kernel<<<1152, 256, 0, stream>>>(a_t, b_t, p_t);
    out_kernel<<<2304, 256, 0, stream>>>(
        p_t, zsrc, out,
        ln_in_w + idx * 128, ln_in_b + idx * 128,
        ln_out_w + idx * 128, ln_out_b + idx * 128,
        wsw5 + 5 * 16384, b_z + idx * 128,
        wsw5 + 4 * 16384, b_g + idx * 128);
  }
}

// Round 10
// 375.392 us; speedup vs baseline: 1.1622x; 1.1622x over previous
//
#include <hip/hip_runtime.h>

// N=384 spatial, C=128 channels (CZ=CH=128). Two tri-mul passes (outgoing, incoming).
// ws layout: [12 swizzled bf16 weight mats | a_t | b_t | p_t], each big buf NN*128 bf16.

constexpr int NS = 384;
constexpr int NN = NS * NS;

using bf16x8 = __attribute__((ext_vector_type(8))) __bf16;
using bf16x4 = __attribute__((ext_vector_type(4))) __bf16;
using f32x4  = __attribute__((ext_vector_type(4))) float;

__device__ inline void load16_to_lds(const __bf16* g, __bf16* lds) {
  auto* gp = reinterpret_cast<const __attribute__((address_space(1))) unsigned int*>(
      reinterpret_cast<uintptr_t>(g));
  auto* lp = reinterpret_cast<__attribute__((address_space(3))) unsigned int*>(
      reinterpret_cast<uintptr_t>(lds));
  __builtin_amdgcn_global_load_lds(gp, lp, 16, 0, 0);
}

// 1/(1+e^-x) with an explicit v_rcp_f32 (ISA: D=1/S0, ~1ulp) instead of the precise
// division chain (~10 instr). Error invisible at bf16 output precision. (verified r3)
__device__ inline float fast_sigmoid(float x) {
  float d = 1.0f + __expf(-x);
  float r;
  asm("v_rcp_f32 %0, %1" : "=v"(r) : "v"(d));
  return r;
}

// ---------------- K0: weight fp32 -> bf16, swizzled to MFMA fragment order ------------
// Fragment slot layout per matrix: idx = ((s*8 + t)*64 + lane)*8 + j  holds
// W[32*s + 8*(lane>>4) + j][16*t + (lane&15)].  (Works as A-op (W^T) or B-op (W).)
__global__ __launch_bounds__(256) void prep_weights(
    const float* __restrict__ w_ag, const float* __restrict__ w_ap,
    const float* __restrict__ w_bg, const float* __restrict__ w_bp,
    const float* __restrict__ w_g,  const float* __restrict__ w_z,
    __bf16* __restrict__ wsw)
{
  int gid  = blockIdx.x * 256 + threadIdx.x;   // 96*256 = 24576 = 12*2048
  int mat  = gid >> 11;
  int slot = gid & 2047;
  int lane = slot & 63;
  int tb   = (slot >> 6) & 7;
  int s    = slot >> 9;
  int pass = mat / 6, which = mat % 6;
  const float* W;
  switch (which) {
    case 0: W = w_ag; break; case 1: W = w_ap; break; case 2: W = w_bg; break;
    case 3: W = w_bp; break; case 4: W = w_g;  break; default: W = w_z;
  }
  W += pass * 16384;
  int n0 = tb * 16 + (lane & 15);
  int k0 = s * 32 + (lane >> 4) * 8;
  __bf16* dst = wsw + ((size_t)mat * 2048 + slot) * 8;
#pragma unroll
  for (int j = 0; j < 8; ++j) dst[j] = (__bf16)W[(k0 + j) * 128 + n0];
}

// Shared LN loader: interleaved channel assignment so load-instruction u fetches bytes
// [u*64, u*64+64) of each of the wave's 16 rows (16 fully-used cache lines / instr,
// vs 64 quarter-used lines in row-sequential order). Thread (row,q) owns channels
// {16u + 4q + j}. sched_barrier(0) pins all 8 loads before the math => 8-deep MLP.
// (verified r7: proj 71->63, out -15us)
template <typename DstRow>
__device__ inline void ln_row_interleaved(const float* __restrict__ zrow, int q,
                                          const float* __restrict__ lnw,
                                          const float* __restrict__ lnb,
                                          DstRow dstrow)
{
  const float4* zp = (const float4*)zrow;
  float4 v[8];
#pragma unroll
  for (int u = 0; u < 8; ++u) v[u] = zp[u * 4 + q];
  __builtin_amdgcn_sched_barrier(0);
  float s1 = 0.f, s2 = 0.f;
#pragma unroll
  for (int u = 0; u < 8; ++u) {
    float4 t = v[u];
    s1 += t.x + t.y + t.z + t.w;
    s2 += t.x * t.x + t.y * t.y + t.z * t.z + t.w * t.w;
  }
  s1 += __shfl_xor(s1, 1); s2 += __shfl_xor(s2, 1);
  s1 += __shfl_xor(s1, 2); s2 += __shfl_xor(s2, 2);
  float mean = s1 * (1.0f / 128.0f);
  float var  = s2 * (1.0f / 128.0f) - mean * mean;
  float rstd = rsqrtf(var + 1e-5f);
#pragma unroll
  for (int u = 0; u < 8; ++u) {
    int c0 = u * 16 + q * 4;
    float4 t  = v[u];
    float4 w4 = *(const float4*)(lnw + c0);
    float4 b4 = *(const float4*)(lnb + c0);
    dstrow[c0 + 0] = (__bf16)((t.x - mean) * rstd * w4.x + b4.x);
    dstrow[c0 + 1] = (__bf16)((t.y - mean) * rstd * w4.y + b4.y);
    dstrow[c0 + 2] = (__bf16)((t.z - mean) * rstd * w4.z + b4.z);
    dstrow[c0 + 3] = (__bf16)((t.w - mean) * rstd * w4.w + b4.w);
  }
}

// ---------------- K2: LN(z) + a, b projections (gates fused) --------------------------
// 128 positions per block (r8, neutral-verified): amortizes per-block weight loads.
// mode 0 (outgoing): block = 128 consecutive positions (row-block).
// mode 1 (incoming): block = 128 positions down a column -> transposed a_t/b_t writes
//                    stay coalesced.
// Output orientation: mfma(znf, fW) -> D[pos][c]; lane's 4 regs are 4 consecutive
// positions of one channel => single 8B store into the [c][pos] layout.
// z fragments re-read from LDS per (set,nt) (keeps VGPR low -> high occupancy, r4).
__global__ __launch_bounds__(256) void proj_kernel(
    const float* __restrict__ zsrc, const float* __restrict__ lnw, const float* __restrict__ lnb,
    const __bf16* __restrict__ wsw5,
    const float* __restrict__ bag, const float* __restrict__ bap,
    const float* __restrict__ bbg, const float* __restrict__ bbp,
    __bf16* __restrict__ a_t, __bf16* __restrict__ b_t, int mode)
{
  __shared__ __bf16 zn[128][136];   // padded pitch: conflict-free b128
  int tid = threadIdx.x;
  int rb = 0, r2 = 0;
  size_t pstart = 0;
  if (mode == 0) pstart = (size_t)blockIdx.x * 128;
  else { rb = blockIdx.x / NS; r2 = blockIdx.x % NS; }   // rb 0..2, r2 0..383

  const int wv = tid >> 6;
  const int lane = tid & 63;
  const int lm = lane & 15;
  const int lq = lane >> 4;

  // ---- phase 1: LayerNorm 128 rows x 128 ch, 4 threads/row, two sequential halves ----
  {
    int row = tid >> 2, q = tid & 3;
#pragma unroll
    for (int half = 0; half < 2; ++half) {
      int r = row + 64 * half;
      size_t zoff = (mode == 0) ? (pstart + r) * 128
                                : ((size_t)(128 * rb + r) * NS + r2) * 128;
      ln_row_interleaved(zsrc + zoff, q, lnw, lnb, &zn[r][0]);
    }
  }
  __syncthreads();

  // ---- phase 2: MFMA projections ----
  const size_t wposbase = (mode == 0) ? pstart : ((size_t)r2 * NS + 128 * rb);

  // sets: 0=(a,mb0) 1=(a,mb1) 2=(b,mb0) 3=(b,mb1)
#pragma unroll
  for (int set = 0; set < 4; ++set) {
    const int grp = set >> 1, mbi = set & 1;
    const int mb = 2 * wv + mbi;   // c_out 16-tile handled by this wave
    const __bf16* wG = wsw5 + (size_t)(2 * grp) * 16384;   // gate weights
    const __bf16* wP = wG + 16384;                         // proj weights
    bf16x8 fG[4], fP[4];
#pragma unroll
    for (int s = 0; s < 4; ++s) {
      fG[s] = *(const bf16x8*)(wG + ((size_t)((s * 8 + mb) * 64 + lane)) * 8);
      fP[s] = *(const bf16x8*)(wP + ((size_t)((s * 8 + mb) * 64 + lane)) * 8);
    }
    const int cc = 16 * mb + lm;       // this lane's output channel
    const float bG = (grp ? bbg : bag)[cc];
    const float bP = (grp ? bbp : bap)[cc];
    __bf16* dst = grp ? b_t : a_t;
    __bf16* drow = dst + (size_t)cc * NN + wposbase + 4 * lq;
#pragma unroll
    for (int nt = 0; nt < 8; ++nt) {
      // z fragments re-read from LDS each iteration (trades LDS BW for registers)
      bf16x8 z0 = *(const bf16x8*)(&zn[16 * nt + lm][8 * lq]);
      bf16x8 z1 = *(const bf16x8*)(&zn[16 * nt + lm][32 + 8 * lq]);
      bf16x8 z2 = *(const bf16x8*)(&zn[16 * nt + lm][64 + 8 * lq]);
      bf16x8 z3 = *(const bf16x8*)(&zn[16 * nt + lm][96 + 8 * lq]);
      f32x4 acc0 = {0.f, 0.f, 0.f, 0.f}, acc1 = {0.f, 0.f, 0.f, 0.f};
      acc0 = __builtin_amdgcn_mfma_f32_16x16x32_bf16(z0, fG[0], acc0, 0, 0, 0);
      acc1 = __builtin_amdgcn_mfma_f32_16x16x32_bf16(z0, fP[0], acc1, 0, 0, 0);
      acc0 = __builtin_amdgcn_mfma_f32_16x16x32_bf16(z1, fG[1], acc0, 0, 0, 0);
      acc1 = __builtin_amdgcn_mfma_f32_16x16x32_bf16(z1, fP[1], acc1, 0, 0, 0);
      acc0 = __builtin_amdgcn_mfma_f32_16x16x32_bf16(z2, fG[2], acc0, 0, 0, 0);
      acc1 = __builtin_amdgcn_mfma_f32_16x16x32_bf16(z2, fP[2], acc1, 0, 0, 0);
      acc0 = __builtin_amdgcn_mfma_f32_16x16x32_bf16(z3, fG[3], acc0, 0, 0, 0);
      acc1 = __builtin_amdgcn_mfma_f32_16x16x32_bf16(z3, fP[3], acc1, 0, 0, 0);
      // D[pos][c]: pos = 16*nt + 4*lq + r (local), c = 16*mb + lm
      bf16x4 pk;
#pragma unroll
      for (int r = 0; r < 4; ++r) {
        float xg = acc0[r] + bG;
        float xp = acc1[r] + bP;
        pk[r] = (__bf16)(xp * fast_sigmoid(xg));
      }
      *(bf16x4*)(drow + 16 * nt) = pk;
    }
  }
}

// ---------------- K3: triangle einsum, per-channel 384x384x384 NT GEMM ----------------
// P[c][i][k] = sum_j A[c][i][j] * B[c][k][j].  128x128 tile/block, BK=64,
// global_load_lds(16B) staging, XOR chunk swizzle => no bank conflicts on ds_read_b128.
// STAGED form (r8, verified ~33us). r9's barrier-free L2-direct variant regressed 2x:
// fragment loads (~200-500cy L2/L3) sit on the per-iteration critical path with only
// ~1 iter of loads in flight (VALUBusy 6%). Staging moves them to 12cy ds_reads and
// inter-block overlap (5 blocks/CU @32KB LDS) hides the global_load_lds latency.
// 1-D grid 1152 with XCD-chunked mapping: XCD k (= lin%8 under round-robin dispatch)
// owns channels [16k,16k+16); each channel's A/B panels stay L2-resident across tiles.
__global__ __launch_bounds__(256) void tri_kernel(
    const __bf16* __restrict__ a_t, const __bf16* __restrict__ b_t, __bf16* __restrict__ p_t)
{
  __shared__ __bf16 As[128 * 64];
  __shared__ __bf16 Bs[128 * 64];
  int lin = blockIdx.x;            // 0..1151
  int xcd = lin & 7;
  int loc = lin >> 3;              // 0..143
  int cq  = loc / 9;               // 0..15
  int tile = loc - 9 * cq;         // 0..8
  int c  = (xcd << 4) | cq;
  int i0 = (tile % 3) * 128, k0 = (tile / 3) * 128;
  const __bf16* Ab = a_t + (size_t)c * NN;
  const __bf16* Bb = b_t + (size_t)c * NN;
  int tid = threadIdx.x, wv = tid >> 6, lane = tid & 63;
  int lm = lane & 15, lq = lane >> 4;
  int lrow = lane >> 3;        // 0..7
  int lsl  = lane & 7;
  int lch  = lsl ^ lrow;       // global chunk this lane fetches (XOR swizzle)
  f32x4 acc[4][4];
#pragma unroll
  for (int mi = 0; mi < 4; ++mi)
#pragma unroll
    for (int ni = 0; ni < 4; ++ni) acc[mi][ni] = {0.f, 0.f, 0.f, 0.f};
  const int rowA_half = 64 * (wv & 1), colB_half = 64 * (wv >> 1);

  for (int kk = 0; kk < 384; kk += 64) {
    __syncthreads();   // previous iteration's LDS reads complete before overwrite
#pragma unroll
    for (int v = 0; v < 4; ++v) {
      int rgrp = 4 * wv + v;                    // 16 groups of 8 rows
      int r = 8 * rgrp + lrow;
      load16_to_lds(Ab + (size_t)(i0 + r) * NS + kk + lch * 8, As + rgrp * 512);
      load16_to_lds(Bb + (size_t)(k0 + r) * NS + kk + lch * 8, Bs + rgrp * 512);
    }
    __syncthreads();   // drains vmcnt for global_load_lds
#pragma unroll
    for (int s = 0; s < 2; ++s) {
      bf16x8 bfr[4], afr[4];
#pragma unroll
      for (int ni = 0; ni < 4; ++ni)
        bfr[ni] = *(const bf16x8*)(Bs + (colB_half + 16 * ni + lm) * 64 +
                                   ((4 * s + lq) ^ (lm & 7)) * 8);
#pragma unroll
      for (int mi = 0; mi < 4; ++mi)
        afr[mi] = *(const bf16x8*)(As + (rowA_half + 16 * mi + lm) * 64 +
                                   ((4 * s + lq) ^ (lm & 7)) * 8);
#pragma unroll
      for (int mi = 0; mi < 4; ++mi)
#pragma unroll
        for (int ni = 0; ni < 4; ++ni)
          acc[mi][ni] = __builtin_amdgcn_mfma_f32_16x16x32_bf16(afr[mi], bfr[ni], acc[mi][ni], 0, 0, 0);
    }
  }
#pragma unroll
  for (int mi = 0; mi < 4; ++mi)
#pragma unroll
    for (int ni = 0; ni < 4; ++ni)
#pragma unroll
      for (int r = 0; r < 4; ++r) {
        int row = i0 + rowA_half + 16 * mi + 4 * lq + r;
        int col = k0 + colB_half + 16 * ni + lm;
        p_t[(size_t)c * NN + (size_t)row * NS + col] = (__bf16)acc[mi][ni][r];
      }
}

// ---------------- K4: LN(p) @ w_z + b_z, g = sigmoid(LN(z) @ w_g + b_g), out = p*g + z -
__global__ __launch_bounds__(256) void out_kernel(
    const __bf16* __restrict__ p_t,
    const float* __restrict__ z_in, float* __restrict__ z_out,
    const float* __restrict__ lniw, const float* __restrict__ lnib,
    const float* __restrict__ lnow, const float* __restrict__ lnob,
    const __bf16* __restrict__ wz, const float* __restrict__ bz,
    const __bf16* __restrict__ wg, const float* __restrict__ bg)
{
  __shared__ __bf16 pl[64][136];
  __shared__ __bf16 znl[64][136];
  int tid = threadIdx.x;
  size_t base = (size_t)blockIdx.x * 64;

  // A. LayerNorm(z) -> znl
  {
    int row = tid >> 2, q = tid & 3;
    ln_row_interleaved(z_in + (base + row) * 128, q, lniw, lnib, &znl[row][0]);
  }

  // B. load P (c-major) coalesced, transpose into LDS [pos][c]  (r7 version; the r8
  // line-coalesced variant regressed ~4us/dispatch — reverted)
  {
    int c2 = tid >> 1, hf = tid & 1;
    const __bf16* src = p_t + (size_t)c2 * NN + base + hf * 32;
    bf16x8 v0 = ((const bf16x8*)src)[0];
    bf16x8 v1 = ((const bf16x8*)src)[1];
    bf16x8 v2 = ((const bf16x8*)src)[2];
    bf16x8 v3 = ((const bf16x8*)src)[3];
#pragma unroll
    for (int j = 0; j < 8; ++j) pl[hf * 32 + j][c2] = v0[j];
#pragma unroll
    for (int j = 0; j < 8; ++j) pl[hf * 32 + 8 + j][c2] = v1[j];
#pragma unroll
    for (int j = 0; j < 8; ++j) pl[hf * 32 + 16 + j][c2] = v2[j];
#pragma unroll
    for (int j = 0; j < 8; ++j) pl[hf * 32 + 24 + j][c2] = v3[j];
  }
  __syncthreads();

  // C. LayerNorm over c per position (4 threads/row), rewrite pl in place
  {
    int row = tid >> 2, q = tid & 3;
    bf16x8 pv[4];
#pragma unroll
    for (int s = 0; s < 4; ++s) pv[s] = *(const bf16x8*)(&pl[row][q * 32 + 8 * s]);
    float s1 = 0.f, s2 = 0.f;
#pragma unroll
    for (int s = 0; s < 4; ++s)
#pragma unroll
      for (int j = 0; j < 8; ++j) { float f = (float)pv[s][j]; s1 += f; s2 += f * f; }
    s1 += __shfl_xor(s1, 1); s2 += __shfl_xor(s2, 1);
    s1 += __shfl_xor(s1, 2); s2 += __shfl_xor(s2, 2);
    float mean = s1 * (1.0f / 128.0f);
    float var  = s2 * (1.0f / 128.0f) - mean * mean;
    float rstd = rsqrtf(var + 1e-5f);
#pragma unroll
    for (int s = 0; s < 4; ++s) {
#pragma unroll
      for (int j = 0; j < 8; ++j) {
        int cc = q * 32 + 8 * s + j;
        float f = ((float)pv[s][j] - mean) * rstd * lnow[cc] + lnob[cc];
        pv[s][j] = (__bf16)f;
      }
      *(bf16x8*)(&pl[row][q * 32 + 8 * s]) = pv[s];
    }
  }
  __syncthreads();

  // D. GEMMs: p_ln @ w_z  and  zn @ w_g; epilogue: (+b_z) * sigmoid(. + b_g) + z
  int wv = tid >> 6, lane = tid & 63, lm = lane & 15, lq = lane >> 4;
  bf16x8 wzf[2][4], wgf[2][4];
  float bzv[2], bgv[2];
#pragma unroll
  for (int nbi = 0; nbi < 2; ++nbi) {
    int nb = 2 * wv + nbi;
    bzv[nbi] = bz[16 * nb + lm];
    bgv[nbi] = bg[16 * nb + lm];
#pragma unroll
    for (int s = 0; s < 4; ++s) {
      wzf[nbi][s] = *(const bf16x8*)(wz + ((size_t)((s * 8 + nb) * 64 + lane)) * 8);
      wgf[nbi][s] = *(const bf16x8*)(wg + ((size_t)((s * 8 + nb) * 64 + lane)) * 8);
    }
  }
#pragma unroll
  for (int mt = 0; mt < 4; ++mt) {
    bf16x8 af[4], zf[4];
#pragma unroll
    for (int s = 0; s < 4; ++s) {
      af[s] = *(const bf16x8*)(&pl[16 * mt + lm][32 * s + 8 * lq]);
      zf[s] = *(const bf16x8*)(&znl[16 * mt + lm][32 * s + 8 * lq]);
    }
#pragma unroll
    for (int nbi = 0; nbi < 2; ++nbi) {
      f32x4 accp = {0.f, 0.f, 0.f, 0.f};
      f32x4 accg = {0.f, 0.f, 0.f, 0.f};
#pragma unroll
      for (int s = 0; s < 4; ++s) {
        accp = __builtin_amdgcn_mfma_f32_16x16x32_bf16(af[s], wzf[nbi][s], accp, 0, 0, 0);
        accg = __builtin_amdgcn_mfma_f32_16x16x32_bf16(zf[s], wgf[nbi][s], accg, 0, 0, 0);
      }
      int cz = 16 * (2 * wv + nbi) + lm;
#pragma unroll
      for (int r = 0; r < 4; ++r) {
        int pos = 16 * mt + 4 * lq + r;
        size_t idx = (base + pos) * 128 + cz;
        float gv  = fast_sigmoid(accg[r] + bgv[nbi]);
        float res = (accp[r] + bzv[nbi]) * gv + z_in[idx];
        z_out[idx] = res;
      }
    }
  }
}

extern "C" void kernel_launch(void* const* d_in, const int* in_sizes, int n_in,
                              void* d_out, int out_size, void* d_ws, size_t ws_size,
                              hipStream_t stream) {
  (void)in_sizes; (void)n_in; (void)out_size; (void)ws_size;
  const float* z        = (const float*)d_in[0];
  const float* ln_in_w  = (const float*)d_in[1];
  const float* ln_in_b  = (const float*)d_in[2];
  const float* w_ag     = (const float*)d_in[3];
  const float* b_ag     = (const float*)d_in[4];
  const float* w_ap     = (const float*)d_in[5];
  const float* b_ap     = (const float*)d_in[6];
  const float* w_bg     = (const float*)d_in[7];
  const float* b_bg     = (const float*)d_in[8];
  const float* w_bp     = (const float*)d_in[9];
  const float* b_bp     = (const float*)d_in[10];
  const float* ln_out_w = (const float*)d_in[11];
  const float* ln_out_b = (const float*)d_in[12];
  const float* w_z      = (const float*)d_in[13];
  const float* b_z      = (const float*)d_in[14];
  const float* w_g      = (const float*)d_in[15];
  const float* b_g      = (const float*)d_in[16];
  float* out = (float*)d_out;

  __bf16* wsw = (__bf16*)d_ws;              // 12 * 16384 elements
  __bf16* a_t = wsw + 12 * 16384;
  __bf16* b_t = a_t + (size_t)NN * 128;
  __bf16* p_t = b_t + (size_t)NN * 128;

  prep_weights<<<96, 256, 0, stream>>>(w_ag, w_ap, w_bg, w_bp, w_g, w_z, wsw);

  for (int idx = 0; idx < 2; ++idx) {
    const float* zsrc = (idx == 0) ? z : out;
    const __bf16* wsw5 = wsw + (size_t)idx * 6 * 16384;
    proj_kernel<<<1152, 256, 0, stream>>>(
        zsrc, ln_in_w + idx * 128, ln_in_b + idx * 128, wsw5,
        b_ag + idx * 128, b_ap + idx * 128, b_bg + idx * 128, b_bp + idx * 128,
        a_t, b_t, idx);
    tri_kernel<<<1152, 256, 0, stream>>>(a_t, b_t, p_t);
    out_kernel<<<2304, 256, 0, stream>>>(
        p_t, zsrc, out,
        ln_in_w + idx * 128, ln_in_b + idx * 128,
        ln_out_w + idx * 128, ln_out_b + idx * 128,
        wsw5 + 5 * 16384, b_z + idx * 128,
        wsw5 + 4 * 16384, b_g + idx * 128);
  }
}